// Round 6
// baseline (8781.023 us; speedup 1.0000x reference)
//
#include <hip/hip_runtime.h>

typedef unsigned int  uint32;
typedef float  f32x4   __attribute__((ext_vector_type(4)));
typedef float  f32x16  __attribute__((ext_vector_type(16)));
typedef __bf16 bf16x8  __attribute__((ext_vector_type(8)));
typedef short  s16x4   __attribute__((ext_vector_type(4)));

__device__ __forceinline__ float bf2f(unsigned int u) {
  return __builtin_bit_cast(float, u << 16);
}
__device__ __forceinline__ unsigned short f2bf(float f) {
  uint32 u = __builtin_bit_cast(uint32, f);
  u += 0x7fffu + ((u >> 16) & 1u);          // RNE
  return (unsigned short)(u >> 16);
}

__device__ __forceinline__ void gload_lds16(const void* g, void* l) {
  __builtin_amdgcn_global_load_lds(
      (const __attribute__((address_space(1))) void*)g,
      (__attribute__((address_space(3))) void*)l, 16, 0, 0);
}

// ---------------- fp32 -> bf16 cast (8 elems/thread) ----------------
__global__ __launch_bounds__(256) void cast_kernel(
    const float* __restrict__ x, unsigned short* __restrict__ y, int n8) {
  int i = blockIdx.x * 256 + threadIdx.x;
  if (i >= n8) return;
  const float4* xp = (const float4*)x;
  float4 a = xp[2 * i], b = xp[2 * i + 1];
  uint4 o;
  o.x = (uint32)f2bf(a.x) | ((uint32)f2bf(a.y) << 16);
  o.y = (uint32)f2bf(a.z) | ((uint32)f2bf(a.w) << 16);
  o.z = (uint32)f2bf(b.x) | ((uint32)f2bf(b.y) << 16);
  o.w = (uint32)f2bf(b.z) | ((uint32)f2bf(b.w) << 16);
  ((uint4*)y)[i] = o;
}

// ---------------- concat two 1024-float bias vectors ----------------
__global__ __launch_bounds__(256) void cat2_kernel(
    const float* __restrict__ a, const float* __restrict__ b,
    float* __restrict__ o) {
  int i = blockIdx.x * 256 + threadIdx.x;
  o[i] = (i < 1024) ? a[i] : b[i - 1024];
}

// ------- bf16 GEMM: C[M,N] = A[M,K] * W[N,K]^T + bias -------
// 256x256 tile, BK=32, 8 waves (2M x 4N), 32x32x16 MFMA, TWO LDS buffers
// (64 KiB -> 2 blocks/CU), counted vmcnt(4) prefetch, raw s_barrier,
// paired-row XOR swizzle (logical row r, 64B: phys byte =
//   (r>>1)*128 + (((r&1)*4 + kq) ^ ((r>>1)&7))*16 + within).
// EPI=0: bf16 out.  EPI=1: fp32 out = acc + bias + resid.
template <int EPI>
__global__ __launch_bounds__(512, 4) void gemm256(
    const unsigned short* __restrict__ A, const unsigned short* __restrict__ W,
    const float* __restrict__ bias, const float* __restrict__ resid,
    unsigned short* __restrict__ Ob, float* __restrict__ Of,
    int M, int N, int K) {
  __shared__ char smem[65536];  // 2 bufs x (A 16KB | B 16KB)
  const int tid  = threadIdx.x;
  const int lane = tid & 63;
  const int wave = tid >> 6;      // 0..7
  const int wr   = wave >> 2;     // 0..1 : m half (128 rows)
  const int wc   = wave & 3;      // 0..3 : n quarter (64 cols)

  // XCD chunk (bijective, nwg%8==0): n-fastest within chunk for A L2-reuse.
  const int nwg = gridDim.x;
  const int xcd = blockIdx.x & 7;
  const int r   = blockIdx.x >> 3;          // 0 .. nwg/8-1
  const int NT  = N >> 8;                   // n-tiles
  const int m0  = (xcd * ((nwg >> 3) / NT) + r / NT) << 8;
  const int n0  = (r % NT) << 8;

  f32x16 acc[4][2];
#pragma unroll
  for (int m = 0; m < 4; ++m)
#pragma unroll
    for (int n = 0; n < 2; ++n) acc[m][n] = (f32x16)0.0f;

  // ---- staging geometry (inverse-swizzled global source, linear LDS dest).
  const int pr8 = lane >> 3;                 // phys row within unit
  const int cl  = (lane & 7) ^ pr8;          // logical chunk (inverse swizzle)
  const int rA0 = (wave * 2) * 16 + pr8 * 2 + (cl >> 2);
  const int kb8 = (cl & 3) * 8;              // k-elem offset 0/8/16/24
  const unsigned short* As0 = A + (size_t)(m0 + rA0) * K + kb8;
  const unsigned short* As1 = As0 + (size_t)16 * K;
  const unsigned short* Bs0 = W + (size_t)(n0 + rA0) * K + kb8;
  const unsigned short* Bs1 = Bs0 + (size_t)16 * K;
  const int dA = wave * 2048 + lane * 16;

#define STAGE(d, kt)                                                          \
  {                                                                           \
    char* sb = smem + (d) * 32768;                                            \
    const int ko = (kt) * 32;                                                 \
    gload_lds16(As0 + ko, sb + dA);                                           \
    gload_lds16(As1 + ko, sb + dA + 1024);                                    \
    gload_lds16(Bs0 + ko, sb + 16384 + dA);                                   \
    gload_lds16(Bs1 + ko, sb + 16384 + dA + 1024);                            \
  }

  // ---- fragment read offsets (swizzled; 2 lanes/chunk per 16-lane group).
  // A-frag (32x32x16): lane L holds row L&31, k = (L>>5)*8 + j.
  const int l31 = lane & 31;
  const int lh  = l31 >> 1;           // (r>>1) within 32-row frag
  const int x7  = lh & 7;
  const int l1  = lane & 1;
  const int hi  = lane >> 5;
  int ck[2];
#pragma unroll
  for (int ks = 0; ks < 2; ++ks)
    ck[ks] = ((l1 * 4 + ks * 2 + hi) ^ x7) * 16;

#define LOADFRAGS(base_, av, bv)                                              \
  _Pragma("unroll") for (int ks = 0; ks < 2; ++ks) {                          \
    _Pragma("unroll") for (int m = 0; m < 4; ++m)                             \
        av[m][ks] = *(const bf16x8*)((base_) + (wr * 64 + m * 16 + lh) * 128  \
                                     + ck[ks]);                               \
    _Pragma("unroll") for (int n = 0; n < 2; ++n)                             \
        bv[n][ks] = *(const bf16x8*)((base_) + 16384                          \
                                     + (wc * 32 + n * 16 + lh) * 128          \
                                     + ck[ks]);                               \
  }

#define DOMFMA(av, bv)                                                        \
  __builtin_amdgcn_s_setprio(1);                                              \
  _Pragma("unroll") for (int m = 0; m < 4; ++m)                               \
      _Pragma("unroll") for (int n = 0; n < 2; ++n)                           \
          _Pragma("unroll") for (int ks = 0; ks < 2; ++ks)                    \
              acc[m][n] = __builtin_amdgcn_mfma_f32_32x32x16_bf16(            \
                  av[m][ks], bv[n][ks], acc[m][n], 0, 0, 0);                  \
  __builtin_amdgcn_s_setprio(0);

  const int nt = K >> 5;  // K-tiles
  STAGE(0, 0);
  STAGE(1, 1);

  for (int t = 0; t < nt - 2; ++t) {
    // Drain to 4 outstanding (= tile t+1) -> tile t's loads landed.
    asm volatile("s_waitcnt vmcnt(4)" ::: "memory");
    __builtin_amdgcn_s_barrier();
    const char* base = smem + (t & 1) * 32768;
    bf16x8 av[4][2], bv[2][2];
    LOADFRAGS(base, av, bv);
    asm volatile("s_waitcnt lgkmcnt(0)" ::: "memory");
    __builtin_amdgcn_s_barrier();          // all waves done reading buf cur
    STAGE(t & 1, t + 2);                   // overwrite it with tile t+2
    DOMFMA(av, bv);
  }
  // tail: tiles nt-2, nt-1
  {
    asm volatile("s_waitcnt vmcnt(4)" ::: "memory");
    __builtin_amdgcn_s_barrier();
    bf16x8 av[4][2], bv[2][2];
    LOADFRAGS(smem + ((nt - 2) & 1) * 32768, av, bv);
    asm volatile("s_waitcnt lgkmcnt(0)" ::: "memory");
    DOMFMA(av, bv);
  }
  {
    asm volatile("s_waitcnt vmcnt(0)" ::: "memory");
    __builtin_amdgcn_s_barrier();
    bf16x8 av[4][2], bv[2][2];
    LOADFRAGS(smem + ((nt - 1) & 1) * 32768, av, bv);
    asm volatile("s_waitcnt lgkmcnt(0)" ::: "memory");
    DOMFMA(av, bv);
  }

  // ---- epilogue: 32x32 C/D map: col = lane&31, row = (reg&3)+8*(reg>>2)+4*hi
#pragma unroll
  for (int n = 0; n < 2; ++n) {
    const int col = n0 + wc * 64 + n * 32 + l31;
    const float bvv = bias[col];
#pragma unroll
    for (int m = 0; m < 4; ++m) {
      const int rowb = m0 + wr * 128 + m * 32 + 4 * hi;
#pragma unroll
      for (int g = 0; g < 16; ++g) {
        const int row = rowb + (g & 3) + 8 * (g >> 2);
        const size_t idx = (size_t)row * N + col;
        float v = acc[m][n][g] + bvv;
        if constexpr (EPI == 0) {
          Ob[idx] = f2bf(v);
        } else {
          Of[idx] = v + resid[idx];
        }
      }
    }
  }
#undef STAGE
#undef LOADFRAGS
#undef DOMFMA
}

// ---------------- head-wise attention, MFMA, one wave per row b ----------
// Q: [B,1024] (qStride 1024). K,V: rows of KV [B,2048]: K at +0, V at +1024.
// Out: [B,1024] with idx = d*16 + h.
__global__ __launch_bounds__(256) void attn_kernel(
    const unsigned short* __restrict__ Q, const unsigned short* __restrict__ KV,
    unsigned short* __restrict__ O) {
  const int tid  = threadIdx.x;
  const int lane = tid & 63;
  const int wave = tid >> 6;
  const int b    = blockIdx.x * 4 + wave;
  const size_t qb  = (size_t)b * 1024;
  const size_t kvb = (size_t)b * 2048;
  const int fr = lane & 15, kg = lane >> 4;

  // ---- QK^T (transposed): A = K rows (g), B = Q rows (h), K-dim = d (64).
  const bf16x8 kf0 = *(const bf16x8*)(KV + kvb + fr * 64 + kg * 8);
  const bf16x8 kf1 = *(const bf16x8*)(KV + kvb + fr * 64 + 32 + kg * 8);
  const bf16x8 qf0 = *(const bf16x8*)(Q + qb + fr * 64 + kg * 8);
  const bf16x8 qf1 = *(const bf16x8*)(Q + qb + fr * 64 + 32 + kg * 8);

  // ---- V B-fragments: lane (fr=d_local, kg) holds V[kg*4+j][c*16+fr].
  s16x4 vb[4];
#pragma unroll
  for (int c = 0; c < 4; ++c) {
    const unsigned short* vp = KV + kvb + 1024 + c * 16 + fr + kg * 4 * 64;
    s16x4 t;
    t[0] = (short)vp[0];
    t[1] = (short)vp[64];
    t[2] = (short)vp[128];
    t[3] = (short)vp[192];
    vb[c] = t;
  }

  f32x4 es = (f32x4)0.0f;
  es = __builtin_amdgcn_mfma_f32_16x16x32_bf16(kf0, qf0, es, 0, 0, 0);
  es = __builtin_amdgcn_mfma_f32_16x16x32_bf16(kf1, qf1, es, 0, 0, 0);

  // ---- softmax over g (rows): in-lane 4 + lanes L^16, L^32.
  float s0 = es[0] * 0.125f, s1 = es[1] * 0.125f;
  float s2 = es[2] * 0.125f, s3 = es[3] * 0.125f;
  float mx = fmaxf(fmaxf(s0, s1), fmaxf(s2, s3));
  mx = fmaxf(mx, __shfl_xor(mx, 16, 64));
  mx = fmaxf(mx, __shfl_xor(mx, 32, 64));
  float e0 = __expf(s0 - mx), e1 = __expf(s1 - mx);
  float e2 = __expf(s2 - mx), e3 = __expf(s3 - mx);
  float sum = e0 + e1 + e2 + e3;
  sum += __shfl_xor(sum, 16, 64);
  sum += __shfl_xor(sum, 32, 64);
  const float inv = 1.0f / sum;

  s16x4 pa;
  pa[0] = (short)f2bf(e0 * inv);
  pa[1] = (short)f2bf(e1 * inv);
  pa[2] = (short)f2bf(e2 * inv);
  pa[3] = (short)f2bf(e3 * inv);

  // ---- PV: out[h, c*16+d'] via 4x mfma 16x16x16 (K = g = 16).
  unsigned short* Ob = O + qb;
#pragma unroll
  for (int c = 0; c < 4; ++c) {
    f32x4 o = __builtin_amdgcn_mfma_f32_16x16x16bf16_1k(pa, vb[c],
                                                        (f32x4)0.0f, 0, 0, 0);
    uint2 st;
    st.x = (uint32)f2bf(o[0]) | ((uint32)f2bf(o[1]) << 16);
    st.y = (uint32)f2bf(o[2]) | ((uint32)f2bf(o[3]) << 16);
    *(uint2*)(Ob + c * 256 + fr * 16 + kg * 4) = st;
  }
}

// ---------------- in-place LayerNorm over rows of 1024 ----------------
__global__ __launch_bounds__(256) void ln_kernel(
    float* __restrict__ Y, const float* __restrict__ gw,
    const float* __restrict__ gb) {
  float* y = Y + (size_t)blockIdx.x * 1024;
  const int tid = threadIdx.x;
  float4 v = ((const float4*)y)[tid];
  float s  = v.x + v.y + v.z + v.w;
  float s2 = v.x * v.x + v.y * v.y + v.z * v.z + v.w * v.w;
#pragma unroll
  for (int o = 32; o > 0; o >>= 1) {
    s  += __shfl_xor(s, o, 64);
    s2 += __shfl_xor(s2, o, 64);
  }
  __shared__ float rs[4], rq[4];
  const int wave = tid >> 6;
  if ((tid & 63) == 0) { rs[wave] = s; rq[wave] = s2; }
  __syncthreads();
  s  = rs[0] + rs[1] + rs[2] + rs[3];
  s2 = rq[0] + rq[1] + rq[2] + rq[3];
  const float mean = s * (1.f / 1024.f);
  const float var  = s2 * (1.f / 1024.f) - mean * mean;
  const float r = rsqrtf(var + 1e-5f);
  const float4 w = ((const float4*)gw)[tid];
  const float4 bb = ((const float4*)gb)[tid];
  float4 o;
  o.x = (v.x - mean) * r * w.x + bb.x;
  o.y = (v.y - mean) * r * w.y + bb.y;
  o.z = (v.z - mean) * r * w.z + bb.z;
  o.w = (v.w - mean) * r * w.w + bb.w;
  ((float4*)y)[tid] = o;
}

extern "C" void kernel_launch(void* const* d_in, const int* in_sizes, int n_in,
                              void* d_out, int out_size, void* d_ws,
                              size_t ws_size, hipStream_t stream) {
  const float* sa = (const float*)d_in[0];
  const float* st = (const float*)d_in[1];
  const float* Wq = (const float*)d_in[2];
  const float* bq = (const float*)d_in[3];
  const float* Wk = (const float*)d_in[4];
  const float* bk = (const float*)d_in[5];
  const float* Wv = (const float*)d_in[6];
  const float* bv = (const float*)d_in[7];
  const float* Wo = (const float*)d_in[8];
  const float* bo = (const float*)d_in[9];
  const float* lw = (const float*)d_in[10];
  const float* lb = (const float*)d_in[11];
  float* out = (float*)d_out;

  const int M = 32768, D = 1024;
  const size_t MiB = 1024 * 1024;
  char* w = (char*)d_ws;
  unsigned short* saB  = (unsigned short*)(w);                // 64 MiB
  unsigned short* stB  = (unsigned short*)(w + 64 * MiB);     // 64 MiB
  unsigned short* WqB  = (unsigned short*)(w + 128 * MiB);    // 2 MiB
  unsigned short* WkvB = (unsigned short*)(w + 130 * MiB);    // 4 MiB (Wk||Wv)
  unsigned short* WoB  = (unsigned short*)(w + 134 * MiB);    // 2 MiB
  unsigned short* Qb   = (unsigned short*)(w + 136 * MiB);    // 64 MiB -> 200 MiB
  float* bkv = (float*)(w + 128 * MiB);  // reuse WqB space (dead after Q gemm)
  // KV [M, 2048] bf16 = exactly 128 MiB -> lives in d_out (dead before O-proj)
  unsigned short* KVb = (unsigned short*)d_out;
  unsigned short* attb = saB;  // sa_bf16 dead after the Q GEMM

  const int nH8 = M * D / 8;
  const int nW8 = D * D / 8;
  cast_kernel<<<nH8 / 256, 256, 0, stream>>>(sa, saB, nH8);
  cast_kernel<<<nH8 / 256, 256, 0, stream>>>(st, stB, nH8);
  cast_kernel<<<nW8 / 256, 256, 0, stream>>>(Wq, WqB, nW8);
  cast_kernel<<<nW8 / 256, 256, 0, stream>>>(Wk, (unsigned short*)WkvB, nW8);
  cast_kernel<<<nW8 / 256, 256, 0, stream>>>(Wv, (unsigned short*)WkvB + D * D, nW8);
  cast_kernel<<<nW8 / 256, 256, 0, stream>>>(Wo, WoB, nW8);

  // Q projection: A=saB. (After this, saB and WqB space are dead.)
  gemm256<0><<<(M / 256) * (D / 256), 512, 0, stream>>>(
      saB, WqB, bq, nullptr, Qb, nullptr, M, D, D);

  // fused K+V projection: A=stB, W=[Wk;Wv], N=2048, C=KV in d_out.
  cat2_kernel<<<8, 256, 0, stream>>>(bk, bv, bkv);
  gemm256<0><<<(M / 256) * (2 * D / 256), 512, 0, stream>>>(
      stB, WkvB, bkv, nullptr, KVb, nullptr, M, 2 * D, D);

  attn_kernel<<<M / 4, 256, 0, stream>>>(Qb, KVb, attb);

  gemm256<1><<<(M / 256) * (D / 256), 512, 0, stream>>>(
      attb, WoB, bo, sa, nullptr, out, M, D, D);

  ln_kernel<<<M, 256, 0, stream>>>(out, lw, lb);
}

// Round 7
// 558.852 us; speedup vs baseline: 15.7126x; 15.7126x over previous
//
#include <hip/hip_runtime.h>

typedef unsigned int  uint32;
typedef float  f32x4   __attribute__((ext_vector_type(4)));
typedef __bf16 bf16x8  __attribute__((ext_vector_type(8)));
typedef short  s16x4   __attribute__((ext_vector_type(4)));

__device__ __forceinline__ float bf2f(unsigned int u) {
  return __builtin_bit_cast(float, u << 16);
}
__device__ __forceinline__ unsigned short f2bf(float f) {
  uint32 u = __builtin_bit_cast(uint32, f);
  u += 0x7fffu + ((u >> 16) & 1u);          // RNE
  return (unsigned short)(u >> 16);
}

__device__ __forceinline__ void gload_lds16(const void* g, void* l) {
  __builtin_amdgcn_global_load_lds(
      (const __attribute__((address_space(1))) void*)g,
      (__attribute__((address_space(3))) void*)l, 16, 0, 0);
}

// ---------------- fp32 -> bf16 cast (8 elems/thread) ----------------
__global__ __launch_bounds__(256) void cast_kernel(
    const float* __restrict__ x, unsigned short* __restrict__ y, int n8) {
  int i = blockIdx.x * 256 + threadIdx.x;
  if (i >= n8) return;
  const float4* xp = (const float4*)x;
  float4 a = xp[2 * i], b = xp[2 * i + 1];
  uint4 o;
  o.x = (uint32)f2bf(a.x) | ((uint32)f2bf(a.y) << 16);
  o.y = (uint32)f2bf(a.z) | ((uint32)f2bf(a.w) << 16);
  o.z = (uint32)f2bf(b.x) | ((uint32)f2bf(b.y) << 16);
  o.w = (uint32)f2bf(b.z) | ((uint32)f2bf(b.w) << 16);
  ((uint4*)y)[i] = o;
}

// ---------------- concat two 1024-float bias vectors ----------------
__global__ __launch_bounds__(256) void cat2_kernel(
    const float* __restrict__ a, const float* __restrict__ b,
    float* __restrict__ o) {
  int i = blockIdx.x * 256 + threadIdx.x;
  o[i] = (i < 1024) ? a[i] : b[i - 1024];
}

// ------- bf16 GEMM: C[M,N] = A[M,K] * W[N,K]^T + bias -------
// (proven round-5 engine, unchanged)
// 256x256 tile, BK=32, 8 waves (2M x 4N), FOUR LDS buffers, 3-tile-deep
// prefetch with counted vmcnt(8), raw s_barrier, paired-row XOR swizzle.
// Block mapping: XCD chunk = 16 m-tiles x NT n-tiles, n-fastest, so
// co-resident blocks on one XCD share A-panels through that XCD's L2.
// EPI=0: bf16 out.  EPI=1: fp32 out = acc + bias + resid.
template <int EPI>
__global__ __launch_bounds__(512, 2) void gemm256(
    const unsigned short* __restrict__ A, const unsigned short* __restrict__ W,
    const float* __restrict__ bias, const float* __restrict__ resid,
    unsigned short* __restrict__ Ob, float* __restrict__ Of,
    int M, int N, int K) {
  __shared__ char smem[131072];  // 4 bufs x (A 16KB | B 16KB)
  const int tid  = threadIdx.x;
  const int lane = tid & 63;
  const int wave = tid >> 6;      // 0..7
  const int wr   = wave >> 2;     // 0..1 : m half (128 rows)
  const int wc   = wave & 3;      // 0..3 : n quarter (64 cols)

  // XCD chunk (bijective, nwg%8==0): n-fastest within chunk for A L2-reuse.
  const int nwg = gridDim.x;
  const int xcd = blockIdx.x & 7;
  const int r   = blockIdx.x >> 3;          // 0 .. nwg/8-1
  const int NT  = N >> 8;                   // n-tiles
  const int m0  = (xcd * ((nwg >> 3) / NT) + r / NT) << 8;
  const int n0  = (r % NT) << 8;

  f32x4 acc[8][4];
#pragma unroll
  for (int m = 0; m < 8; ++m)
#pragma unroll
    for (int n = 0; n < 4; ++n) acc[m][n] = (f32x4)0.0f;

  // ---- staging geometry (inverse-swizzled global source, linear LDS dest).
  const int pr8 = lane >> 3;                 // phys row within unit
  const int cl  = (lane & 7) ^ pr8;          // logical chunk (inverse swizzle)
  const int rA0 = (wave * 2) * 16 + pr8 * 2 + (cl >> 2);
  const int kb8 = (cl & 3) * 8;              // k-elem offset 0/8/16/24
  const unsigned short* As0 = A + (size_t)(m0 + rA0) * K + kb8;
  const unsigned short* As1 = As0 + (size_t)16 * K;
  const unsigned short* Bs0 = W + (size_t)(n0 + rA0) * K + kb8;
  const unsigned short* Bs1 = Bs0 + (size_t)16 * K;
  const int dA = wave * 2048 + lane * 16;

#define STAGE(d, kt)                                                          \
  {                                                                           \
    char* sb = smem + (d) * 32768;                                            \
    const int ko = (kt) * 32;                                                 \
    gload_lds16(As0 + ko, sb + dA);                                           \
    gload_lds16(As1 + ko, sb + dA + 1024);                                    \
    gload_lds16(Bs0 + ko, sb + 16384 + dA);                                   \
    gload_lds16(Bs1 + ko, sb + 16384 + dA + 1024);                            \
  }

  // ---- fragment read offsets (swizzled), conflict-free.
  const int fr  = lane & 15, kg = lane >> 4, frh = fr >> 1;
  const int cA  = ((((fr & 1) * 4) + kg) ^ frh) * 16;
  const int aoff = (wr * 64 + frh) * 128 + cA;            // + m*1024
  const int boff = 16384 + (wc * 32 + frh) * 128 + cA;    // + n*1024

#define MFMAS(base_)                                                          \
  {                                                                           \
    bf16x8 av[8], bv[4];                                                      \
    _Pragma("unroll") for (int m = 0; m < 8; ++m)                             \
        av[m] = *(const bf16x8*)((base_) + aoff + m * 1024);                  \
    _Pragma("unroll") for (int n = 0; n < 4; ++n)                             \
        bv[n] = *(const bf16x8*)((base_) + boff + n * 1024);                  \
    __builtin_amdgcn_s_setprio(1);                                            \
    _Pragma("unroll") for (int m = 0; m < 8; ++m)                             \
        _Pragma("unroll") for (int n = 0; n < 4; ++n)                         \
            acc[m][n] = __builtin_amdgcn_mfma_f32_16x16x32_bf16(              \
                av[m], bv[n], acc[m][n], 0, 0, 0);                            \
    __builtin_amdgcn_s_setprio(0);                                            \
  }

  const int nt = K >> 5;  // 32 K-tiles
  STAGE(0, 0);
  STAGE(1, 1);
  STAGE(2, 2);

  for (int t = 0; t < nt - 3; ++t) {
    // Drain until only tiles t+1,t+2 (2 tiles x 4 loads = 8) remain in
    // flight -> tile t's loads (oldest, in-order retire) have landed.
    asm volatile("s_waitcnt vmcnt(8)" ::: "memory");
    __builtin_amdgcn_s_barrier();
    const char* base = smem + (t & 3) * 32768;
    bf16x8 av[8], bv[4];
#pragma unroll
    for (int m = 0; m < 8; ++m)
      av[m] = *(const bf16x8*)(base + aoff + m * 1024);
#pragma unroll
    for (int n = 0; n < 4; ++n)
      bv[n] = *(const bf16x8*)(base + boff + n * 1024);
    STAGE((t + 3) & 3, t + 3);   // into buffer freed at end of iter t-1
    __builtin_amdgcn_s_setprio(1);
#pragma unroll
    for (int m = 0; m < 8; ++m)
#pragma unroll
      for (int n = 0; n < 4; ++n)
        acc[m][n] = __builtin_amdgcn_mfma_f32_16x16x32_bf16(av[m], bv[n],
                                                            acc[m][n], 0, 0, 0);
    __builtin_amdgcn_s_setprio(0);
    // all my ds_reads of buf t&3 done -> buffer reusable after barrier
    asm volatile("s_waitcnt lgkmcnt(0)" ::: "memory");
    __builtin_amdgcn_s_barrier();
  }
  // tail: tiles nt-3, nt-2, nt-1 (no more staging)
  asm volatile("s_waitcnt vmcnt(8)" ::: "memory");
  __builtin_amdgcn_s_barrier();
  MFMAS(smem + ((nt - 3) & 3) * 32768);
  asm volatile("s_waitcnt vmcnt(4)" ::: "memory");
  __builtin_amdgcn_s_barrier();
  MFMAS(smem + ((nt - 2) & 3) * 32768);
  asm volatile("s_waitcnt vmcnt(0)" ::: "memory");
  __builtin_amdgcn_s_barrier();
  MFMAS(smem + ((nt - 1) & 3) * 32768);

  // ---- epilogue: C/D frag mapping col = lane&15, row = (lane>>4)*4 + i
  const int r4 = (lane >> 4) * 4;
#pragma unroll
  for (int n = 0; n < 4; ++n) {
    const int col = n0 + wc * 64 + n * 16 + fr;
    const float bvv = bias[col];
#pragma unroll
    for (int m = 0; m < 8; ++m) {
      const int row = m0 + wr * 128 + m * 16 + r4;
#pragma unroll
      for (int i = 0; i < 4; ++i) {
        const size_t idx = (size_t)(row + i) * N + col;
        float v = acc[m][n][i] + bvv;
        if constexpr (EPI == 0) {
          Ob[idx] = f2bf(v);
        } else {
          Of[idx] = v + resid[idx];
        }
      }
    }
  }
#undef STAGE
#undef MFMAS
}

// ---------------- head-wise attention, MFMA, one wave per row b ----------
// Q: [B,1024].  K,V packed in KV [B,2048]: K at +0, V at +1024.
// Out: [B,1024] with idx = d*16 + h.
__global__ __launch_bounds__(256) void attn_kernel(
    const unsigned short* __restrict__ Q, const unsigned short* __restrict__ KV,
    unsigned short* __restrict__ O) {
  const int tid  = threadIdx.x;
  const int lane = tid & 63;
  const int wave = tid >> 6;
  const int b    = blockIdx.x * 4 + wave;
  const size_t qb  = (size_t)b * 1024;
  const size_t kvb = (size_t)b * 2048;
  const int fr = lane & 15, kg = lane >> 4;

  // ---- QK^T (transposed): A = K rows (g), B = Q rows (h), K-dim = d (64).
  const bf16x8 kf0 = *(const bf16x8*)(KV + kvb + fr * 64 + kg * 8);
  const bf16x8 kf1 = *(const bf16x8*)(KV + kvb + fr * 64 + 32 + kg * 8);
  const bf16x8 qf0 = *(const bf16x8*)(Q + qb + fr * 64 + kg * 8);
  const bf16x8 qf1 = *(const bf16x8*)(Q + qb + fr * 64 + 32 + kg * 8);

  // ---- V B-fragments: lane (fr=d_local, kg) holds V[kg*4+j][c*16+fr].
  s16x4 vb[4];
#pragma unroll
  for (int c = 0; c < 4; ++c) {
    const unsigned short* vp = KV + kvb + 1024 + c * 16 + fr + kg * 4 * 64;
    s16x4 t;
    t[0] = (short)vp[0];
    t[1] = (short)vp[64];
    t[2] = (short)vp[128];
    t[3] = (short)vp[192];
    vb[c] = t;
  }

  f32x4 es = (f32x4)0.0f;
  es = __builtin_amdgcn_mfma_f32_16x16x32_bf16(kf0, qf0, es, 0, 0, 0);
  es = __builtin_amdgcn_mfma_f32_16x16x32_bf16(kf1, qf1, es, 0, 0, 0);

  // ---- softmax over g (rows): in-lane 4 + lanes L^16, L^32.
  float s0 = es[0] * 0.125f, s1 = es[1] * 0.125f;
  float s2 = es[2] * 0.125f, s3 = es[3] * 0.125f;
  float mx = fmaxf(fmaxf(s0, s1), fmaxf(s2, s3));
  mx = fmaxf(mx, __shfl_xor(mx, 16, 64));
  mx = fmaxf(mx, __shfl_xor(mx, 32, 64));
  float e0 = __expf(s0 - mx), e1 = __expf(s1 - mx);
  float e2 = __expf(s2 - mx), e3 = __expf(s3 - mx);
  float sum = e0 + e1 + e2 + e3;
  sum += __shfl_xor(sum, 16, 64);
  sum += __shfl_xor(sum, 32, 64);
  const float inv = 1.0f / sum;

  s16x4 pa;
  pa[0] = (short)f2bf(e0 * inv);
  pa[1] = (short)f2bf(e1 * inv);
  pa[2] = (short)f2bf(e2 * inv);
  pa[3] = (short)f2bf(e3 * inv);

  // ---- PV: out[h, c*16+d'] via 4x mfma 16x16x16 (K = g = 16).
  unsigned short* Ob = O + qb;
#pragma unroll
  for (int c = 0; c < 4; ++c) {
    f32x4 o = __builtin_amdgcn_mfma_f32_16x16x16bf16_1k(pa, vb[c],
                                                        (f32x4)0.0f, 0, 0, 0);
    uint2 st;
    st.x = (uint32)f2bf(o[0]) | ((uint32)f2bf(o[1]) << 16);
    st.y = (uint32)f2bf(o[2]) | ((uint32)f2bf(o[3]) << 16);
    *(uint2*)(Ob + c * 256 + fr * 16 + kg * 4) = st;
  }
}

// ---------------- in-place LayerNorm over rows of 1024 ----------------
__global__ __launch_bounds__(256) void ln_kernel(
    float* __restrict__ Y, const float* __restrict__ gw,
    const float* __restrict__ gb) {
  float* y = Y + (size_t)blockIdx.x * 1024;
  const int tid = threadIdx.x;
  float4 v = ((const float4*)y)[tid];
  float s  = v.x + v.y + v.z + v.w;
  float s2 = v.x * v.x + v.y * v.y + v.z * v.z + v.w * v.w;
#pragma unroll
  for (int o = 32; o > 0; o >>= 1) {
    s  += __shfl_xor(s, o, 64);
    s2 += __shfl_xor(s2, o, 64);
  }
  __shared__ float rs[4], rq[4];
  const int wave = tid >> 6;
  if ((tid & 63) == 0) { rs[wave] = s; rq[wave] = s2; }
  __syncthreads();
  s  = rs[0] + rs[1] + rs[2] + rs[3];
  s2 = rq[0] + rq[1] + rq[2] + rq[3];
  const float mean = s * (1.f / 1024.f);
  const float var  = s2 * (1.f / 1024.f) - mean * mean;
  const float r = rsqrtf(var + 1e-5f);
  const float4 w = ((const float4*)gw)[tid];
  const float4 bb = ((const float4*)gb)[tid];
  float4 o;
  o.x = (v.x - mean) * r * w.x + bb.x;
  o.y = (v.y - mean) * r * w.y + bb.y;
  o.z = (v.z - mean) * r * w.z + bb.z;
  o.w = (v.w - mean) * r * w.w + bb.w;
  ((float4*)y)[tid] = o;
}

extern "C" void kernel_launch(void* const* d_in, const int* in_sizes, int n_in,
                              void* d_out, int out_size, void* d_ws,
                              size_t ws_size, hipStream_t stream) {
  const float* sa = (const float*)d_in[0];
  const float* st = (const float*)d_in[1];
  const float* Wq = (const float*)d_in[2];
  const float* bq = (const float*)d_in[3];
  const float* Wk = (const float*)d_in[4];
  const float* bk = (const float*)d_in[5];
  const float* Wv = (const float*)d_in[6];
  const float* bv = (const float*)d_in[7];
  const float* Wo = (const float*)d_in[8];
  const float* bo = (const float*)d_in[9];
  const float* lw = (const float*)d_in[10];
  const float* lb = (const float*)d_in[11];
  float* out = (float*)d_out;

  const int M = 32768, D = 1024;
  const size_t MiB = 1024 * 1024;
  char* w = (char*)d_ws;
  unsigned short* saB  = (unsigned short*)(w);                // 64 MiB
  unsigned short* stB  = (unsigned short*)(w + 64 * MiB);     // 64 MiB
  unsigned short* WqB  = (unsigned short*)(w + 128 * MiB);    // 2 MiB
  unsigned short* WkvB = (unsigned short*)(w + 130 * MiB);    // 4 MiB (Wk||Wv)
  unsigned short* WoB  = (unsigned short*)(w + 134 * MiB);    // 2 MiB
  unsigned short* Qb   = (unsigned short*)(w + 136 * MiB);    // 64 MiB -> 200 MiB
  float* bkv = (float*)(w + 128 * MiB);  // reuse WqB space (dead after Q gemm)
  // KV [M, 2048] bf16 = exactly 128 MiB -> lives in d_out (dead before O-proj)
  unsigned short* KVb = (unsigned short*)d_out;
  unsigned short* attb = saB;  // sa_bf16 dead after the Q GEMM

  const int nH8 = M * D / 8;
  const int nW8 = D * D / 8;
  cast_kernel<<<nH8 / 256, 256, 0, stream>>>(sa, saB, nH8);
  cast_kernel<<<nH8 / 256, 256, 0, stream>>>(st, stB, nH8);
  cast_kernel<<<nW8 / 256, 256, 0, stream>>>(Wq, WqB, nW8);
  cast_kernel<<<nW8 / 256, 256, 0, stream>>>(Wk, (unsigned short*)WkvB, nW8);
  cast_kernel<<<nW8 / 256, 256, 0, stream>>>(Wv, (unsigned short*)WkvB + D * D, nW8);
  cast_kernel<<<nW8 / 256, 256, 0, stream>>>(Wo, WoB, nW8);

  // Q projection: A=saB. (After this, saB and WqB space are dead.)
  gemm256<0><<<(M / 256) * (D / 256), 512, 0, stream>>>(
      saB, WqB, bq, nullptr, Qb, nullptr, M, D, D);

  // fused K+V projection: A=stB, W=[Wk;Wv], N=2048, C=KV in d_out.
  cat2_kernel<<<8, 256, 0, stream>>>(bk, bv, bkv);
  gemm256<0><<<(M / 256) * (2 * D / 256), 512, 0, stream>>>(
      stB, WkvB, bkv, nullptr, KVb, nullptr, M, 2 * D, D);

  attn_kernel<<<M / 4, 256, 0, stream>>>(Qb, KVb, attb);

  gemm256<1><<<(M / 256) * (D / 256), 512, 0, stream>>>(
      attb, WoB, bo, sa, nullptr, out, M, D, D);

  ln_kernel<<<M, 256, 0, stream>>>(out, lw, lb);
}

// Round 8
// 551.468 us; speedup vs baseline: 15.9230x; 1.0134x over previous
//
#include <hip/hip_runtime.h>

typedef unsigned int  uint32;
typedef float  f32x4   __attribute__((ext_vector_type(4)));
typedef __bf16 bf16x8  __attribute__((ext_vector_type(8)));
typedef short  s16x4   __attribute__((ext_vector_type(4)));

__device__ __forceinline__ float bf2f(unsigned int u) {
  return __builtin_bit_cast(float, u << 16);
}
__device__ __forceinline__ unsigned short f2bf(float f) {
  uint32 u = __builtin_bit_cast(uint32, f);
  u += 0x7fffu + ((u >> 16) & 1u);          // RNE
  return (unsigned short)(u >> 16);
}

__device__ __forceinline__ void gload_lds16(const void* g, void* l) {
  __builtin_amdgcn_global_load_lds(
      (const __attribute__((address_space(1))) void*)g,
      (__attribute__((address_space(3))) void*)l, 16, 0, 0);
}

// ---------------- fp32 -> bf16 cast (8 elems/thread) ----------------
__global__ __launch_bounds__(256) void cast_kernel(
    const float* __restrict__ x, unsigned short* __restrict__ y, int n8) {
  int i = blockIdx.x * 256 + threadIdx.x;
  if (i >= n8) return;
  const float4* xp = (const float4*)x;
  float4 a = xp[2 * i], b = xp[2 * i + 1];
  uint4 o;
  o.x = (uint32)f2bf(a.x) | ((uint32)f2bf(a.y) << 16);
  o.y = (uint32)f2bf(a.z) | ((uint32)f2bf(a.w) << 16);
  o.z = (uint32)f2bf(b.x) | ((uint32)f2bf(b.y) << 16);
  o.w = (uint32)f2bf(b.z) | ((uint32)f2bf(b.w) << 16);
  ((uint4*)y)[i] = o;
}

// ---------------- concat two 1024-float bias vectors ----------------
__global__ __launch_bounds__(256) void cat2_kernel(
    const float* __restrict__ a, const float* __restrict__ b,
    float* __restrict__ o) {
  int i = blockIdx.x * 256 + threadIdx.x;
  o[i] = (i < 1024) ? a[i] : b[i - 1024];
}

// ------- bf16 GEMM: C[M,N] = A[M,K] * W[N,K]^T + bias -------
// Round-7 engine + T3 phase-split K-tile body (2 pinned phases/tile).
// 256x256 tile, BK=32, 8 waves (2M x 4N), FOUR LDS buffers, 3-tile-deep
// prefetch with counted vmcnt(8), raw s_barrier, paired-row XOR swizzle.
// EPI=0: bf16 out.  EPI=1: fp32 out = acc + bias + resid.
template <int EPI>
__global__ __launch_bounds__(512, 2) void gemm256(
    const unsigned short* __restrict__ A, const unsigned short* __restrict__ W,
    const float* __restrict__ bias, const float* __restrict__ resid,
    unsigned short* __restrict__ Ob, float* __restrict__ Of,
    int M, int N, int K) {
  __shared__ char smem[131072];  // 4 bufs x (A 16KB | B 16KB)
  const int tid  = threadIdx.x;
  const int lane = tid & 63;
  const int wave = tid >> 6;      // 0..7
  const int wr   = wave >> 2;     // 0..1 : m half (128 rows)
  const int wc   = wave & 3;      // 0..3 : n quarter (64 cols)

  // XCD chunk (bijective, nwg%8==0): n-fastest within chunk for A L2-reuse.
  const int nwg = gridDim.x;
  const int xcd = blockIdx.x & 7;
  const int r   = blockIdx.x >> 3;          // 0 .. nwg/8-1
  const int NT  = N >> 8;                   // n-tiles
  const int m0  = (xcd * ((nwg >> 3) / NT) + r / NT) << 8;
  const int n0  = (r % NT) << 8;

  f32x4 acc[8][4];
#pragma unroll
  for (int m = 0; m < 8; ++m)
#pragma unroll
    for (int n = 0; n < 4; ++n) acc[m][n] = (f32x4)0.0f;

  // ---- staging geometry (inverse-swizzled global source, linear LDS dest).
  const int pr8 = lane >> 3;                 // phys row within unit
  const int cl  = (lane & 7) ^ pr8;          // logical chunk (inverse swizzle)
  const int rA0 = (wave * 2) * 16 + pr8 * 2 + (cl >> 2);
  const int kb8 = (cl & 3) * 8;              // k-elem offset 0/8/16/24
  const unsigned short* As0 = A + (size_t)(m0 + rA0) * K + kb8;
  const unsigned short* As1 = As0 + (size_t)16 * K;
  const unsigned short* Bs0 = W + (size_t)(n0 + rA0) * K + kb8;
  const unsigned short* Bs1 = Bs0 + (size_t)16 * K;
  const int dA = wave * 2048 + lane * 16;

#define STAGE_A(d, kt)                                                        \
  {                                                                           \
    char* sb = smem + (d) * 32768;                                            \
    const int ko = (kt) * 32;                                                 \
    gload_lds16(As0 + ko, sb + dA);                                           \
    gload_lds16(As1 + ko, sb + dA + 1024);                                    \
  }
#define STAGE_B(d, kt)                                                        \
  {                                                                           \
    char* sb = smem + (d) * 32768;                                            \
    const int ko = (kt) * 32;                                                 \
    gload_lds16(Bs0 + ko, sb + 16384 + dA);                                   \
    gload_lds16(Bs1 + ko, sb + 16384 + dA + 1024);                            \
  }

  // ---- fragment read offsets (swizzled), conflict-free.
  const int fr  = lane & 15, kg = lane >> 4, frh = fr >> 1;
  const int cA  = ((((fr & 1) * 4) + kg) ^ frh) * 16;
  const int aoff = (wr * 64 + frh) * 128 + cA;            // + m*1024
  const int boff = 16384 + (wc * 32 + frh) * 128 + cA;    // + n*1024

#define MFMAS(base_)                                                          \
  {                                                                           \
    bf16x8 av[8], bv[4];                                                      \
    _Pragma("unroll") for (int m = 0; m < 8; ++m)                             \
        av[m] = *(const bf16x8*)((base_) + aoff + m * 1024);                  \
    _Pragma("unroll") for (int n = 0; n < 4; ++n)                             \
        bv[n] = *(const bf16x8*)((base_) + boff + n * 1024);                  \
    __builtin_amdgcn_s_setprio(1);                                            \
    _Pragma("unroll") for (int m = 0; m < 8; ++m)                             \
        _Pragma("unroll") for (int n = 0; n < 4; ++n)                         \
            acc[m][n] = __builtin_amdgcn_mfma_f32_16x16x32_bf16(              \
                av[m], bv[n], acc[m][n], 0, 0, 0);                            \
    __builtin_amdgcn_s_setprio(0);                                            \
  }

  const int nt = K >> 5;  // 32 K-tiles
  STAGE_A(0, 0); STAGE_B(0, 0);
  STAGE_A(1, 1); STAGE_B(1, 1);
  STAGE_A(2, 2); STAGE_B(2, 2);

  for (int t = 0; t < nt - 3; ++t) {
    // Drain until only tiles t+1,t+2 (2 tiles x 4 loads = 8) remain in
    // flight -> tile t's loads (oldest, in-order retire) have landed.
    asm volatile("s_waitcnt vmcnt(8)" ::: "memory");
    __builtin_amdgcn_s_barrier();
    const char* base = smem + (t & 3) * 32768;

    // ---- phase 1: read lower A-half + all B ; stage next A-half ; MFMA m0-3
    bf16x8 a0[4], bv[4];
#pragma unroll
    for (int m = 0; m < 4; ++m)
      a0[m] = *(const bf16x8*)(base + aoff + m * 1024);
#pragma unroll
    for (int n = 0; n < 4; ++n)
      bv[n] = *(const bf16x8*)(base + boff + n * 1024);
    STAGE_A((t + 3) & 3, t + 3);
    asm volatile("s_waitcnt lgkmcnt(0)" ::: "memory");
    __builtin_amdgcn_sched_barrier(0);
    __builtin_amdgcn_s_setprio(1);
#pragma unroll
    for (int m = 0; m < 4; ++m)
#pragma unroll
      for (int n = 0; n < 4; ++n)
        acc[m][n] = __builtin_amdgcn_mfma_f32_16x16x32_bf16(a0[m], bv[n],
                                                            acc[m][n], 0, 0, 0);
    __builtin_amdgcn_s_setprio(0);
    __builtin_amdgcn_sched_barrier(0);

    // ---- phase 2: read upper A-half (lands under phase-1 MFMA drain);
    //      stage next B-half ; MFMA m4-7 (independent acc regs).
    bf16x8 a1[4];
#pragma unroll
    for (int m = 0; m < 4; ++m)
      a1[m] = *(const bf16x8*)(base + aoff + (m + 4) * 1024);
    STAGE_B((t + 3) & 3, t + 3);
    asm volatile("s_waitcnt lgkmcnt(0)" ::: "memory");
    __builtin_amdgcn_sched_barrier(0);
    __builtin_amdgcn_s_setprio(1);
#pragma unroll
    for (int m = 0; m < 4; ++m)
#pragma unroll
      for (int n = 0; n < 4; ++n)
        acc[m + 4][n] = __builtin_amdgcn_mfma_f32_16x16x32_bf16(
            a1[m], bv[n], acc[m + 4][n], 0, 0, 0);
    __builtin_amdgcn_s_setprio(0);
    // all my ds_reads of buf t&3 done -> buffer reusable after barrier
    asm volatile("s_waitcnt lgkmcnt(0)" ::: "memory");
    __builtin_amdgcn_s_barrier();
  }
  // tail: tiles nt-3, nt-2, nt-1 (no more staging)
  asm volatile("s_waitcnt vmcnt(8)" ::: "memory");
  __builtin_amdgcn_s_barrier();
  MFMAS(smem + ((nt - 3) & 3) * 32768);
  asm volatile("s_waitcnt vmcnt(4)" ::: "memory");
  __builtin_amdgcn_s_barrier();
  MFMAS(smem + ((nt - 2) & 3) * 32768);
  asm volatile("s_waitcnt vmcnt(0)" ::: "memory");
  __builtin_amdgcn_s_barrier();
  MFMAS(smem + ((nt - 1) & 3) * 32768);

  // ---- epilogue: C/D frag mapping col = lane&15, row = (lane>>4)*4 + i
  const int r4 = (lane >> 4) * 4;
#pragma unroll
  for (int n = 0; n < 4; ++n) {
    const int col = n0 + wc * 64 + n * 16 + fr;
    const float bvv = bias[col];
#pragma unroll
    for (int m = 0; m < 8; ++m) {
      const int row = m0 + wr * 128 + m * 16 + r4;
#pragma unroll
      for (int i = 0; i < 4; ++i) {
        const size_t idx = (size_t)(row + i) * N + col;
        float v = acc[m][n][i] + bvv;
        if constexpr (EPI == 0) {
          Ob[idx] = f2bf(v);
        } else {
          Of[idx] = v + resid[idx];
        }
      }
    }
  }
#undef STAGE_A
#undef STAGE_B
#undef MFMAS
}

// ---------------- head-wise attention, MFMA, one wave per row b ----------
// Q: [B,1024].  K,V packed in KV [B,2048]: K at +0, V at +1024.
// Out: [B,1024] with idx = d*16 + h.
__global__ __launch_bounds__(256) void attn_kernel(
    const unsigned short* __restrict__ Q, const unsigned short* __restrict__ KV,
    unsigned short* __restrict__ O) {
  const int tid  = threadIdx.x;
  const int lane = tid & 63;
  const int wave = tid >> 6;
  const int b    = blockIdx.x * 4 + wave;
  const size_t qb  = (size_t)b * 1024;
  const size_t kvb = (size_t)b * 2048;
  const int fr = lane & 15, kg = lane >> 4;

  // ---- QK^T (transposed): A = K rows (g), B = Q rows (h), K-dim = d (64).
  const bf16x8 kf0 = *(const bf16x8*)(KV + kvb + fr * 64 + kg * 8);
  const bf16x8 kf1 = *(const bf16x8*)(KV + kvb + fr * 64 + 32 + kg * 8);
  const bf16x8 qf0 = *(const bf16x8*)(Q + qb + fr * 64 + kg * 8);
  const bf16x8 qf1 = *(const bf16x8*)(Q + qb + fr * 64 + 32 + kg * 8);

  // ---- V B-fragments: lane (fr=d_local, kg) holds V[kg*4+j][c*16+fr].
  s16x4 vb[4];
#pragma unroll
  for (int c = 0; c < 4; ++c) {
    const unsigned short* vp = KV + kvb + 1024 + c * 16 + fr + kg * 4 * 64;
    s16x4 t;
    t[0] = (short)vp[0];
    t[1] = (short)vp[64];
    t[2] = (short)vp[128];
    t[3] = (short)vp[192];
    vb[c] = t;
  }

  f32x4 es = (f32x4)0.0f;
  es = __builtin_amdgcn_mfma_f32_16x16x32_bf16(kf0, qf0, es, 0, 0, 0);
  es = __builtin_amdgcn_mfma_f32_16x16x32_bf16(kf1, qf1, es, 0, 0, 0);

  // ---- softmax over g (rows): in-lane 4 + lanes L^16, L^32.
  float s0 = es[0] * 0.125f, s1 = es[1] * 0.125f;
  float s2 = es[2] * 0.125f, s3 = es[3] * 0.125f;
  float mx = fmaxf(fmaxf(s0, s1), fmaxf(s2, s3));
  mx = fmaxf(mx, __shfl_xor(mx, 16, 64));
  mx = fmaxf(mx, __shfl_xor(mx, 32, 64));
  float e0 = __expf(s0 - mx), e1 = __expf(s1 - mx);
  float e2 = __expf(s2 - mx), e3 = __expf(s3 - mx);
  float sum = e0 + e1 + e2 + e3;
  sum += __shfl_xor(sum, 16, 64);
  sum += __shfl_xor(sum, 32, 64);
  const float inv = 1.0f / sum;

  s16x4 pa;
  pa[0] = (short)f2bf(e0 * inv);
  pa[1] = (short)f2bf(e1 * inv);
  pa[2] = (short)f2bf(e2 * inv);
  pa[3] = (short)f2bf(e3 * inv);

  // ---- PV: out[h, c*16+d'] via 4x mfma 16x16x16 (K = g = 16).
  unsigned short* Ob = O + qb;
#pragma unroll
  for (int c = 0; c < 4; ++c) {
    f32x4 o = __builtin_amdgcn_mfma_f32_16x16x16bf16_1k(pa, vb[c],
                                                        (f32x4)0.0f, 0, 0, 0);
    uint2 st;
    st.x = (uint32)f2bf(o[0]) | ((uint32)f2bf(o[1]) << 16);
    st.y = (uint32)f2bf(o[2]) | ((uint32)f2bf(o[3]) << 16);
    *(uint2*)(Ob + c * 256 + fr * 16 + kg * 4) = st;
  }
}

// ---------------- in-place LayerNorm over rows of 1024 ----------------
__global__ __launch_bounds__(256) void ln_kernel(
    float* __restrict__ Y, const float* __restrict__ gw,
    const float* __restrict__ gb) {
  float* y = Y + (size_t)blockIdx.x * 1024;
  const int tid = threadIdx.x;
  float4 v = ((const float4*)y)[tid];
  float s  = v.x + v.y + v.z + v.w;
  float s2 = v.x * v.x + v.y * v.y + v.z * v.z + v.w * v.w;
#pragma unroll
  for (int o = 32; o > 0; o >>= 1) {
    s  += __shfl_xor(s, o, 64);
    s2 += __shfl_xor(s2, o, 64);
  }
  __shared__ float rs[4], rq[4];
  const int wave = tid >> 6;
  if ((tid & 63) == 0) { rs[wave] = s; rq[wave] = s2; }
  __syncthreads();
  s  = rs[0] + rs[1] + rs[2] + rs[3];
  s2 = rq[0] + rq[1] + rq[2] + rq[3];
  const float mean = s * (1.f / 1024.f);
  const float var  = s2 * (1.f / 1024.f) - mean * mean;
  const float r = rsqrtf(var + 1e-5f);
  const float4 w = ((const float4*)gw)[tid];
  const float4 bb = ((const float4*)gb)[tid];
  float4 o;
  o.x = (v.x - mean) * r * w.x + bb.x;
  o.y = (v.y - mean) * r * w.y + bb.y;
  o.z = (v.z - mean) * r * w.z + bb.z;
  o.w = (v.w - mean) * r * w.w + bb.w;
  ((float4*)y)[tid] = o;
}

extern "C" void kernel_launch(void* const* d_in, const int* in_sizes, int n_in,
                              void* d_out, int out_size, void* d_ws,
                              size_t ws_size, hipStream_t stream) {
  const float* sa = (const float*)d_in[0];
  const float* st = (const float*)d_in[1];
  const float* Wq = (const float*)d_in[2];
  const float* bq = (const float*)d_in[3];
  const float* Wk = (const float*)d_in[4];
  const float* bk = (const float*)d_in[5];
  const float* Wv = (const float*)d_in[6];
  const float* bv = (const float*)d_in[7];
  const float* Wo = (const float*)d_in[8];
  const float* bo = (const float*)d_in[9];
  const float* lw = (const float*)d_in[10];
  const float* lb = (const float*)d_in[11];
  float* out = (float*)d_out;

  const int M = 32768, D = 1024;
  const size_t MiB = 1024 * 1024;
  char* w = (char*)d_ws;
  unsigned short* saB  = (unsigned short*)(w);                // 64 MiB
  unsigned short* stB  = (unsigned short*)(w + 64 * MiB);     // 64 MiB
  unsigned short* WqB  = (unsigned short*)(w + 128 * MiB);    // 2 MiB
  unsigned short* WkvB = (unsigned short*)(w + 130 * MiB);    // 4 MiB (Wk||Wv)
  unsigned short* WoB  = (unsigned short*)(w + 134 * MiB);    // 2 MiB
  unsigned short* Qb   = (unsigned short*)(w + 136 * MiB);    // 64 MiB -> 200 MiB
  float* bkv = (float*)(w + 128 * MiB);  // reuse WqB space (dead after Q gemm)
  // KV [M, 2048] bf16 = exactly 128 MiB -> lives in d_out (dead before O-proj)
  unsigned short* KVb = (unsigned short*)d_out;
  unsigned short* attb = saB;  // sa_bf16 dead after the Q GEMM

  const int nH8 = M * D / 8;
  const int nW8 = D * D / 8;
  cast_kernel<<<nH8 / 256, 256, 0, stream>>>(sa, saB, nH8);
  cast_kernel<<<nH8 / 256, 256, 0, stream>>>(st, stB, nH8);
  cast_kernel<<<nW8 / 256, 256, 0, stream>>>(Wq, WqB, nW8);
  cast_kernel<<<nW8 / 256, 256, 0, stream>>>(Wk, (unsigned short*)WkvB, nW8);
  cast_kernel<<<nW8 / 256, 256, 0, stream>>>(Wv, (unsigned short*)WkvB + D * D, nW8);
  cast_kernel<<<nW8 / 256, 256, 0, stream>>>(Wo, WoB, nW8);

  // Q projection: A=saB. (After this, saB and WqB space are dead.)
  gemm256<0><<<(M / 256) * (D / 256), 512, 0, stream>>>(
      saB, WqB, bq, nullptr, Qb, nullptr, M, D, D);

  // fused K+V projection: A=stB, W=[Wk;Wv], N=2048, C=KV in d_out.
  cat2_kernel<<<8, 256, 0, stream>>>(bk, bv, bkv);
  gemm256<0><<<(M / 256) * (2 * D / 256), 512, 0, stream>>>(
      stB, WkvB, bkv, nullptr, KVb, nullptr, M, 2 * D, D);

  attn_kernel<<<M / 4, 256, 0, stream>>>(Qb, KVb, attb);

  gemm256<1><<<(M / 256) * (D / 256), 512, 0, stream>>>(
      attb, WoB, bo, sa, nullptr, out, M, D, D);

  ln_kernel<<<M, 256, 0, stream>>>(out, lw, lb);
}

// Round 9
// 501.641 us; speedup vs baseline: 17.5046x; 1.0993x over previous
//
#include <hip/hip_runtime.h>

typedef unsigned int  uint32;
typedef float  f32x4   __attribute__((ext_vector_type(4)));
typedef __bf16 bf16x8  __attribute__((ext_vector_type(8)));
typedef short  s16x4   __attribute__((ext_vector_type(4)));

__device__ __forceinline__ float bf2f(unsigned int u) {
  return __builtin_bit_cast(float, u << 16);
}
__device__ __forceinline__ unsigned short f2bf(float f) {
  uint32 u = __builtin_bit_cast(uint32, f);
  u += 0x7fffu + ((u >> 16) & 1u);          // RNE
  return (unsigned short)(u >> 16);
}

__device__ __forceinline__ void gload_lds16(const void* g, void* l) {
  __builtin_amdgcn_global_load_lds(
      (const __attribute__((address_space(1))) void*)g,
      (__attribute__((address_space(3))) void*)l, 16, 0, 0);
}

// ---------------- fp32 -> bf16 cast (8 elems/thread) ----------------
__global__ __launch_bounds__(256) void cast_kernel(
    const float* __restrict__ x, unsigned short* __restrict__ y, int n8) {
  int i = blockIdx.x * 256 + threadIdx.x;
  if (i >= n8) return;
  const float4* xp = (const float4*)x;
  float4 a = xp[2 * i], b = xp[2 * i + 1];
  uint4 o;
  o.x = (uint32)f2bf(a.x) | ((uint32)f2bf(a.y) << 16);
  o.y = (uint32)f2bf(a.z) | ((uint32)f2bf(a.w) << 16);
  o.z = (uint32)f2bf(b.x) | ((uint32)f2bf(b.y) << 16);
  o.w = (uint32)f2bf(b.z) | ((uint32)f2bf(b.w) << 16);
  ((uint4*)y)[i] = o;
}

// ---------------- concat two 1024-float bias vectors ----------------
__global__ __launch_bounds__(256) void cat2_kernel(
    const float* __restrict__ a, const float* __restrict__ b,
    float* __restrict__ o) {
  int i = blockIdx.x * 256 + threadIdx.x;
  o[i] = (i < 1024) ? a[i] : b[i - 1024];
}

// ------- bf16 GEMM: C[M,N] = A[M,K] * W[N,K]^T + bias -------
// 256x256 tile, BK=64, 8 waves (2M x 4N), TWO LDS buffers (2 x 64KB),
// 2-tile-deep prefetch with counted vmcnt(8), raw s_barrier,
// st_16x32-style XOR swizzle (row 128B: chunk16 ^= row&7).
// K-tile body = 4 quadrant phases x 16 MFMA (bounded operand registers).
// EPI=0: bf16 out.  EPI=1: fp32 out = acc + bias + resid.
template <int EPI>
__global__ __launch_bounds__(512, 2) void gemm256(
    const unsigned short* __restrict__ A, const unsigned short* __restrict__ W,
    const float* __restrict__ bias, const float* __restrict__ resid,
    unsigned short* __restrict__ Ob, float* __restrict__ Of,
    int M, int N, int K) {
  __shared__ char smem[131072];  // 2 bufs x (A 32KB | B 32KB)
  const int tid  = threadIdx.x;
  const int lane = tid & 63;
  const int wave = tid >> 6;      // 0..7
  const int wr   = wave >> 2;     // 0..1 : m half (128 rows)
  const int wc   = wave & 3;      // 0..3 : n quarter (64 cols)

  // XCD chunk (bijective, nwg%8==0): n-fastest within chunk for A L2-reuse.
  const int nwg = gridDim.x;
  const int xcd = blockIdx.x & 7;
  const int r   = blockIdx.x >> 3;          // 0 .. nwg/8-1
  const int NT  = N >> 8;                   // n-tiles
  const int m0  = (xcd * ((nwg >> 3) / NT) + r / NT) << 8;
  const int n0  = (r % NT) << 8;

  f32x4 acc[8][4];
#pragma unroll
  for (int m = 0; m < 8; ++m)
#pragma unroll
    for (int n = 0; n < 4; ++n) acc[m][n] = (f32x4)0.0f;

  // ---- staging geometry (inverse-swizzled global source, linear LDS dest).
  // Load j covers rows j*64 + wave*8 + (lane>>3); 16B chunk cl of the row,
  // cl = (lane&7) ^ (lane>>3)  (inverse of the read-side XOR).
  const int pr8 = lane >> 3;
  const int cl  = (lane & 7) ^ pr8;
  const unsigned short* As = A + (size_t)(m0 + wave * 8 + pr8) * K + cl * 8;
  const unsigned short* Bs = W + (size_t)(n0 + wave * 8 + pr8) * K + cl * 8;
  const int dst = wave * 1024 + lane * 16;

#define STAGE(d, kt)                                                          \
  {                                                                           \
    char* sb = smem + (d) * 65536;                                            \
    const int ko = (kt) * 64;                                                 \
    _Pragma("unroll") for (int j = 0; j < 4; ++j)                             \
        gload_lds16(As + (size_t)(j * 64) * K + ko, sb + j * 8192 + dst);     \
    _Pragma("unroll") for (int j = 0; j < 4; ++j)                             \
        gload_lds16(Bs + (size_t)(j * 64) * K + ko,                           \
                    sb + 32768 + j * 8192 + dst);                             \
  }

  // ---- fragment read offsets (swizzled): row r, k-chunk c (= ks*4+kg):
  // byte = r*128 + ((c ^ (r&7))*16.  row&7 == fr&7 for all fragments.
  const int fr = lane & 15, kg = lane >> 4;
  int cA[2];
#pragma unroll
  for (int ks = 0; ks < 2; ++ks)
    cA[ks] = fr * 128 + (((ks * 4 + kg) ^ (fr & 7)) * 16);
  const int abase = wr * 16384;           // + m*2048 + cA[ks]
  const int bbase = 32768 + wc * 8192;    // + n*2048 + cA[ks]

#define PH_AB(base_, av_, bv_, mlo, ks)                                       \
  {                                                                           \
    _Pragma("unroll") for (int m = 0; m < 4; ++m)                             \
        av_[m] = *(const bf16x8*)((base_) + abase + ((mlo) + m) * 2048 +      \
                                  cA[ks]);                                    \
    _Pragma("unroll") for (int n = 0; n < 4; ++n)                             \
        bv_[n] = *(const bf16x8*)((base_) + bbase + n * 2048 + cA[ks]);       \
  }
#define PH_A(base_, av_, mlo, ks)                                             \
  {                                                                           \
    _Pragma("unroll") for (int m = 0; m < 4; ++m)                             \
        av_[m] = *(const bf16x8*)((base_) + abase + ((mlo) + m) * 2048 +      \
                                  cA[ks]);                                    \
  }
#define PH_MFMA(av_, bv_, mlo)                                                \
  __builtin_amdgcn_s_setprio(1);                                              \
  _Pragma("unroll") for (int m = 0; m < 4; ++m)                               \
      _Pragma("unroll") for (int n = 0; n < 4; ++n)                           \
          acc[(mlo) + m][n] = __builtin_amdgcn_mfma_f32_16x16x32_bf16(        \
              av_[m], bv_[n], acc[(mlo) + m][n], 0, 0, 0);                    \
  __builtin_amdgcn_s_setprio(0);

  const int nt = K >> 6;  // 64-wide K-tiles (16 for K=1024)
  STAGE(0, 0);
  STAGE(1, 1);

  for (int t = 0; t < nt - 2; ++t) {
    // in flight: t (8) + t+1 (8).  Drain to 8 -> tile t landed.
    asm volatile("s_waitcnt vmcnt(8)" ::: "memory");
    __builtin_amdgcn_s_barrier();
    const char* base = smem + (t & 1) * 65536;
    bf16x8 a0[4], a1[4], b0[4], b1[4];
    // phase A: ks0 m0-3
    PH_AB(base, a0, b0, 0, 0);
    PH_MFMA(a0, b0, 0);
    // phase B: ks0 m4-7
    PH_A(base, a1, 4, 0);
    PH_MFMA(a1, b0, 4);
    // phase C: ks1 m0-3
    PH_AB(base, a0, b1, 0, 1);
    PH_MFMA(a0, b1, 0);
    // phase D: ks1 m4-7 -- last reads of this buffer
    PH_A(base, a1, 4, 1);
    asm volatile("s_waitcnt lgkmcnt(0)" ::: "memory");
    __builtin_amdgcn_s_barrier();          // all waves done reading buf
    STAGE(t & 1, t + 2);                   // overwrite with tile t+2
    __builtin_amdgcn_sched_barrier(0);
    PH_MFMA(a1, b1, 4);
  }
  // tail: tiles nt-2 (vmcnt 8) and nt-1 (vmcnt 0), no staging
#pragma unroll
  for (int tt = 0; tt < 2; ++tt) {
    if (tt == 0)
      asm volatile("s_waitcnt vmcnt(8)" ::: "memory");
    else
      asm volatile("s_waitcnt vmcnt(0)" ::: "memory");
    __builtin_amdgcn_s_barrier();
    const char* base = smem + ((nt - 2 + tt) & 1) * 65536;
    bf16x8 a0[4], a1[4], b0[4], b1[4];
    PH_AB(base, a0, b0, 0, 0);
    PH_MFMA(a0, b0, 0);
    PH_A(base, a1, 4, 0);
    PH_MFMA(a1, b0, 4);
    PH_AB(base, a0, b1, 0, 1);
    PH_MFMA(a0, b1, 0);
    PH_A(base, a1, 4, 1);
    PH_MFMA(a1, b1, 4);
  }

  // ---- epilogue: C/D map col = lane&15, row = (lane>>4)*4 + i.
  // Row-major store order (m,i outer; n inner) so each row's 4 chunks
  // issue back-to-back -> L2 write-sector merge (fix 1.8x write amp).
  const int r4 = (lane >> 4) * 4;
  float bvv[4];
#pragma unroll
  for (int n = 0; n < 4; ++n) bvv[n] = bias[n0 + wc * 64 + n * 16 + fr];
#pragma unroll
  for (int m = 0; m < 8; ++m) {
    const int rowb = m0 + wr * 128 + m * 16 + r4;
#pragma unroll
    for (int i = 0; i < 4; ++i) {
      const size_t rb = (size_t)(rowb + i) * N;
#pragma unroll
      for (int n = 0; n < 4; ++n) {
        const size_t idx = rb + (n0 + wc * 64 + n * 16 + fr);
        float v = acc[m][n][i] + bvv[n];
        if constexpr (EPI == 0) {
          Ob[idx] = f2bf(v);
        } else {
          Of[idx] = v + resid[idx];
        }
      }
    }
  }
#undef STAGE
#undef PH_AB
#undef PH_A
#undef PH_MFMA
}

// ---------------- head-wise attention, MFMA, one wave per row b ----------
// Q: [B,1024].  K,V packed in KV [B,2048]: K at +0, V at +1024.
// Out: [B,1024] with idx = d*16 + h.
__global__ __launch_bounds__(256) void attn_kernel(
    const unsigned short* __restrict__ Q, const unsigned short* __restrict__ KV,
    unsigned short* __restrict__ O) {
  const int tid  = threadIdx.x;
  const int lane = tid & 63;
  const int wave = tid >> 6;
  const int b    = blockIdx.x * 4 + wave;
  const size_t qb  = (size_t)b * 1024;
  const size_t kvb = (size_t)b * 2048;
  const int fr = lane & 15, kg = lane >> 4;

  // ---- QK^T (transposed): A = K rows (g), B = Q rows (h), K-dim = d (64).
  const bf16x8 kf0 = *(const bf16x8*)(KV + kvb + fr * 64 + kg * 8);
  const bf16x8 kf1 = *(const bf16x8*)(KV + kvb + fr * 64 + 32 + kg * 8);
  const bf16x8 qf0 = *(const bf16x8*)(Q + qb + fr * 64 + kg * 8);
  const bf16x8 qf1 = *(const bf16x8*)(Q + qb + fr * 64 + 32 + kg * 8);

  // ---- V B-fragments: lane (fr=d_local, kg) holds V[kg*4+j][c*16+fr].
  s16x4 vb[4];
#pragma unroll
  for (int c = 0; c < 4; ++c) {
    const unsigned short* vp = KV + kvb + 1024 + c * 16 + fr + kg * 4 * 64;
    s16x4 t;
    t[0] = (short)vp[0];
    t[1] = (short)vp[64];
    t[2] = (short)vp[128];
    t[3] = (short)vp[192];
    vb[c] = t;
  }

  f32x4 es = (f32x4)0.0f;
  es = __builtin_amdgcn_mfma_f32_16x16x32_bf16(kf0, qf0, es, 0, 0, 0);
  es = __builtin_amdgcn_mfma_f32_16x16x32_bf16(kf1, qf1, es, 0, 0, 0);

  // ---- softmax over g (rows): in-lane 4 + lanes L^16, L^32.
  float s0 = es[0] * 0.125f, s1 = es[1] * 0.125f;
  float s2 = es[2] * 0.125f, s3 = es[3] * 0.125f;
  float mx = fmaxf(fmaxf(s0, s1), fmaxf(s2, s3));
  mx = fmaxf(mx, __shfl_xor(mx, 16, 64));
  mx = fmaxf(mx, __shfl_xor(mx, 32, 64));
  float e0 = __expf(s0 - mx), e1 = __expf(s1 - mx);
  float e2 = __expf(s2 - mx), e3 = __expf(s3 - mx);
  float sum = e0 + e1 + e2 + e3;
  sum += __shfl_xor(sum, 16, 64);
  sum += __shfl_xor(sum, 32, 64);
  const float inv = 1.0f / sum;

  s16x4 pa;
  pa[0] = (short)f2bf(e0 * inv);
  pa[1] = (short)f2bf(e1 * inv);
  pa[2] = (short)f2bf(e2 * inv);
  pa[3] = (short)f2bf(e3 * inv);

  // ---- PV: out[h, c*16+d'] via 4x mfma 16x16x16 (K = g = 16).
  unsigned short* Ob = O + qb;
#pragma unroll
  for (int c = 0; c < 4; ++c) {
    f32x4 o = __builtin_amdgcn_mfma_f32_16x16x16bf16_1k(pa, vb[c],
                                                        (f32x4)0.0f, 0, 0, 0);
    uint2 st;
    st.x = (uint32)f2bf(o[0]) | ((uint32)f2bf(o[1]) << 16);
    st.y = (uint32)f2bf(o[2]) | ((uint32)f2bf(o[3]) << 16);
    *(uint2*)(Ob + c * 256 + fr * 16 + kg * 4) = st;
  }
}

// ---------------- in-place LayerNorm over rows of 1024 ----------------
__global__ __launch_bounds__(256) void ln_kernel(
    float* __restrict__ Y, const float* __restrict__ gw,
    const float* __restrict__ gb) {
  float* y = Y + (size_t)blockIdx.x * 1024;
  const int tid = threadIdx.x;
  float4 v = ((const float4*)y)[tid];
  float s  = v.x + v.y + v.z + v.w;
  float s2 = v.x * v.x + v.y * v.y + v.z * v.z + v.w * v.w;
#pragma unroll
  for (int o = 32; o > 0; o >>= 1) {
    s  += __shfl_xor(s, o, 64);
    s2 += __shfl_xor(s2, o, 64);
  }
  __shared__ float rs[4], rq[4];
  const int wave = tid >> 6;
  if ((tid & 63) == 0) { rs[wave] = s; rq[wave] = s2; }
  __syncthreads();
  s  = rs[0] + rs[1] + rs[2] + rs[3];
  s2 = rq[0] + rq[1] + rq[2] + rq[3];
  const float mean = s * (1.f / 1024.f);
  const float var  = s2 * (1.f / 1024.f) - mean * mean;
  const float r = rsqrtf(var + 1e-5f);
  const float4 w = ((const float4*)gw)[tid];
  const float4 bb = ((const float4*)gb)[tid];
  float4 o;
  o.x = (v.x - mean) * r * w.x + bb.x;
  o.y = (v.y - mean) * r * w.y + bb.y;
  o.z = (v.z - mean) * r * w.z + bb.z;
  o.w = (v.w - mean) * r * w.w + bb.w;
  ((float4*)y)[tid] = o;
}

extern "C" void kernel_launch(void* const* d_in, const int* in_sizes, int n_in,
                              void* d_out, int out_size, void* d_ws,
                              size_t ws_size, hipStream_t stream) {
  const float* sa = (const float*)d_in[0];
  const float* st = (const float*)d_in[1];
  const float* Wq = (const float*)d_in[2];
  const float* bq = (const float*)d_in[3];
  const float* Wk = (const float*)d_in[4];
  const float* bk = (const float*)d_in[5];
  const float* Wv = (const float*)d_in[6];
  const float* bv = (const float*)d_in[7];
  const float* Wo = (const float*)d_in[8];
  const float* bo = (const float*)d_in[9];
  const float* lw = (const float*)d_in[10];
  const float* lb = (const float*)d_in[11];
  float* out = (float*)d_out;

  const int M = 32768, D = 1024;
  const size_t MiB = 1024 * 1024;
  char* w = (char*)d_ws;
  unsigned short* saB  = (unsigned short*)(w);                // 64 MiB
  unsigned short* stB  = (unsigned short*)(w + 64 * MiB);     // 64 MiB
  unsigned short* WqB  = (unsigned short*)(w + 128 * MiB);    // 2 MiB
  unsigned short* WkvB = (unsigned short*)(w + 130 * MiB);    // 4 MiB (Wk||Wv)
  unsigned short* WoB  = (unsigned short*)(w + 134 * MiB);    // 2 MiB
  unsigned short* Qb   = (unsigned short*)(w + 136 * MiB);    // 64 MiB -> 200 MiB
  float* bkv = (float*)(w + 128 * MiB);  // reuse WqB space (dead after Q gemm)
  // KV [M, 2048] bf16 = exactly 128 MiB -> lives in d_out (dead before O-proj)
  unsigned short* KVb = (unsigned short*)d_out;
  unsigned short* attb = saB;  // sa_bf16 dead after the Q GEMM

  const int nH8 = M * D / 8;
  const int nW8 = D * D / 8;
  cast_kernel<<<nH8 / 256, 256, 0, stream>>>(sa, saB, nH8);
  cast_kernel<<<nH8 / 256, 256, 0, stream>>>(st, stB, nH8);
  cast_kernel<<<nW8 / 256, 256, 0, stream>>>(Wq, WqB, nW8);
  cast_kernel<<<nW8 / 256, 256, 0, stream>>>(Wk, (unsigned short*)WkvB, nW8);
  cast_kernel<<<nW8 / 256, 256, 0, stream>>>(Wv, (unsigned short*)WkvB + D * D, nW8);
  cast_kernel<<<nW8 / 256, 256, 0, stream>>>(Wo, WoB, nW8);

  // Q projection: A=saB. (After this, saB and WqB space are dead.)
  gemm256<0><<<(M / 256) * (D / 256), 512, 0, stream>>>(
      saB, WqB, bq, nullptr, Qb, nullptr, M, D, D);

  // fused K+V projection: A=stB, W=[Wk;Wv], N=2048, C=KV in d_out.
  cat2_kernel<<<8, 256, 0, stream>>>(bk, bv, bkv);
  gemm256<0><<<(M / 256) * (2 * D / 256), 512, 0, stream>>>(
      stB, WkvB, bkv, nullptr, KVb, nullptr, M, 2 * D, D);

  attn_kernel<<<M / 4, 256, 0, stream>>>(Qb, KVb, attb);

  gemm256<1><<<(M / 256) * (D / 256), 512, 0, stream>>>(
      attb, WoB, bo, sa, nullptr, out, M, D, D);

  ln_kernel<<<M, 256, 0, stream>>>(out, lw, lb);
}